// Round 3
// baseline (11887.596 us; speedup 1.0000x reference)
//
#include <hip/hip_runtime.h>
#include <stdint.h>

// mLSTM T=512,B=256,I=H=512 — fp32-equivalent via fp16 hi/lo MFMA (3-pass).
// NOTE: harness delivers integer inputs as int32 -> lengths is const int*.
// ws layout (bytes):
//   xh     @ 0          x hi fp16                 134,217,728
//   xl     @ 134217728  x lo fp16 (scaled 2^11)   134,217,728
//   wpre_h @ 268435456  [W_ih;mx_w] frags hi        2,621,440
//   wpre_l @ 271056896  lo                          2,621,440
//   wrec_h @ 273678336  [W_hh;mh_w] frags hi        2,621,440
//   wrec_l @ 276299776  lo                          2,621,440
//   blob   @ 278921216  xg/xm fp32, 1 chunk of 128 steps 335,544,320
//   hbh    @ 614465536  h hi plane [256][512]         262,144
//   hbl    @ 614727680  h lo plane                    262,144
//   mbh    @ 614989824  m hi plane                    262,144
//   mbl    @ 615251968  m lo plane                    262,144
//   cbuf   @ 615514112  c state fp32                  524,288
//   flags  @ 616038400  8 barrier counters                512
// total 616,038,912

typedef __attribute__((ext_vector_type(8))) short s8v;
typedef __attribute__((ext_vector_type(8))) _Float16 h8v;
typedef __attribute__((ext_vector_type(4))) float f4v;

#define SC 2048.0f
#define ISC (1.0f / 2048.0f)

__device__ __forceinline__ f4v mf(s8v a, s8v b, f4v c) {
  return __builtin_amdgcn_mfma_f32_16x16x32_f16(
      __builtin_bit_cast(h8v, a), __builtin_bit_cast(h8v, b), c, 0, 0, 0);
}
__device__ __forceinline__ uint16_t f2h(float x) {
  _Float16 h = (_Float16)x;
  return __builtin_bit_cast(uint16_t, h);
}
__device__ __forceinline__ void split2(float v, uint16_t& hi, uint16_t& lo) {
  _Float16 h = (_Float16)v;
  float r = v - (float)h;
  hi = __builtin_bit_cast(uint16_t, h);
  lo = f2h(r * SC);
}
__device__ __forceinline__ float sigm(float x) { return 1.0f / (1.0f + __expf(-x)); }
__device__ __forceinline__ float tanh_f(float x) { return 1.0f - 2.0f / (__expf(2.0f * x) + 1.0f); }

// ---------------- split x fp32 -> fp16 hi/lo planes ----------------
__global__ __launch_bounds__(256) void k_split(const float* __restrict__ x,
                                               uint16_t* __restrict__ xh,
                                               uint16_t* __restrict__ xl, long n) {
  long i = ((long)blockIdx.x * 256 + threadIdx.x) * 8;
  if (i >= n) return;
  float4 a = *(const float4*)(x + i);
  float4 b = *(const float4*)(x + i + 4);
  union { uint16_t u[8]; s8v v; } oh, ol;
  float vv[8] = {a.x, a.y, a.z, a.w, b.x, b.y, b.z, b.w};
#pragma unroll
  for (int k = 0; k < 8; ++k) split2(vv[k], oh.u[k], ol.u[k]);
  *(s8v*)(xh + i) = oh.v;
  *(s8v*)(xl + i) = ol.v;
}

// ---------------- pack weights into MFMA B-fragment order, hi/lo ----------------
// strip s<128: gate col 16s+c from Wg; s>=128: col 16(s-128)+c from Wm
// frag[(s*16+kt)*512 + lane*8 + j] = W_col[k = kt*32 + 8*(lane>>4) + j]
__global__ __launch_bounds__(64) void k_packw(const float* __restrict__ Wg,
                                              const float* __restrict__ Wm,
                                              uint16_t* __restrict__ wh,
                                              uint16_t* __restrict__ wl) {
  int s = blockIdx.x >> 4, kt = blockIdx.x & 15, l = threadIdx.x;
  const float* src = (s < 128) ? (Wg + (size_t)(s * 16 + (l & 15)) * 512)
                               : (Wm + (size_t)((s - 128) * 16 + (l & 15)) * 512);
  int k0 = kt * 32 + (l >> 4) * 8;
  float4 a = *(const float4*)(src + k0);
  float4 b = *(const float4*)(src + k0 + 4);
  union { uint16_t u[8]; s8v v; } oh, ol;
  float vv[8] = {a.x, a.y, a.z, a.w, b.x, b.y, b.z, b.w};
#pragma unroll
  for (int k = 0; k < 8; ++k) split2(vv[k], oh.u[k], ol.u[k]);
  size_t adr = ((size_t)(s * 16 + kt) * 64 + l) * 8;
  *(s8v*)(wh + adr) = oh.v;
  *(s8v*)(wl + adr) = ol.v;
}

// ---------------- one K-pass of the precompute GEMM ----------------
__device__ __forceinline__ void gpass(const uint16_t* __restrict__ Ap,
                                      const uint16_t* __restrict__ Bp,
                                      s8v* Asm, s8v* Bsm, int rowbase, int s0,
                                      f4v (&acc)[4][4]) {
  int tid = threadIdx.x;
  int wv = tid >> 6, l = tid & 63, wm = wv >> 1, wn = wv & 1;
  int arow = tid >> 1, ahalf = tid & 1, swz = (arow & 7) << 4;
  for (int ks = 0; ks < 8; ++ks) {
    __syncthreads();
    const uint16_t* asrc = Ap + (size_t)(rowbase + arow) * 512 + ks * 64;
#pragma unroll
    for (int q = 0; q < 4; ++q) {
      int pb = ahalf * 64 + q * 16;  // physical byte within 128B row
      Asm[arow * 8 + (pb >> 4)] = *(const s8v*)(asrc + ((pb ^ swz) >> 1));
    }
#pragma unroll
    for (int q = 0; q < 4; ++q) {
      int ofs = tid * 64 + q * 16;
      int si = ofs >> 11, kti = (ofs >> 10) & 1, inner = ofs & 1023;
      Bsm[ofs >> 4] =
          *(const s8v*)(Bp + (size_t)((s0 + si) * 16 + ks * 2 + kti) * 512 + (inner >> 1));
    }
    __syncthreads();
#pragma unroll
    for (int kti = 0; kti < 2; ++kti) {
      s8v a[4], b[4];
#pragma unroll
      for (int i = 0; i < 4; ++i) {
        int row = wm * 64 + i * 16 + (l & 15);
        int lb = kti * 64 + (l >> 4) * 16;  // logical byte within row
        a[i] = Asm[row * 8 + ((lb ^ ((l & 7) << 4)) >> 4)];
      }
#pragma unroll
      for (int jj = 0; jj < 4; ++jj) b[jj] = Bsm[((wn * 4 + jj) * 2 + kti) * 64 + l];
#pragma unroll
      for (int i = 0; i < 4; ++i)
#pragma unroll
        for (int jj = 0; jj < 4; ++jj) acc[i][jj] = mf(a[i], b[jj], acc[i][jj]);
    }
  }
}

// ---------------- 3-pass precompute GEMM, fp32 blob out ----------------
// blob tile layout per chunk: [(t*160+s)*8+g]*512 + rr*16 + c  (fp32)
__global__ __launch_bounds__(256, 2) void k_gemm3(const uint16_t* __restrict__ xh,
                                                  const uint16_t* __restrict__ xl,
                                                  const uint16_t* __restrict__ wh,
                                                  const uint16_t* __restrict__ wl,
                                                  float* __restrict__ blob, int row0) {
  __shared__ s8v Asm[1024], Bsm[1024];
  f4v acc_a[4][4], acc_c[4][4];
#pragma unroll
  for (int i = 0; i < 4; ++i)
#pragma unroll
    for (int jj = 0; jj < 4; ++jj) {
      acc_a[i][jj] = (f4v){0.f, 0.f, 0.f, 0.f};
      acc_c[i][jj] = (f4v){0.f, 0.f, 0.f, 0.f};
    }
  int s0 = blockIdx.x * 8, r0 = blockIdx.y * 128;
  int rowbase = row0 + r0;
  gpass(xh, wh, Asm, Bsm, rowbase, s0, acc_a);
  gpass(xh, wl, Asm, Bsm, rowbase, s0, acc_c);
  gpass(xl, wh, Asm, Bsm, rowbase, s0, acc_c);
  int tid = threadIdx.x, wv = tid >> 6, l = tid & 63, wm = wv >> 1, wn = wv & 1;
#pragma unroll
  for (int i = 0; i < 4; ++i)
#pragma unroll
    for (int jj = 0; jj < 4; ++jj) {
      int s = s0 + wn * 4 + jj;
#pragma unroll
      for (int ri = 0; ri < 4; ++ri) {
        int trow = r0 + wm * 64 + i * 16 + (l >> 4) * 4 + ri;  // chunk-local row
        int tt = trow >> 8, gg = (trow >> 5) & 7, rr = trow & 31;
        size_t adr = ((size_t)(tt * 160 + s) * 8 + gg) * 512 + rr * 16 + (l & 15);
        blob[adr] = acc_a[i][jj][ri] + acc_c[i][jj][ri] * ISC;
      }
    }
}

// ---------------- group barrier (32 WGs per batch-group) ----------------
__device__ __forceinline__ void grp_barrier(uint32_t* cnt, uint32_t tgt) {
  asm volatile("s_waitcnt vmcnt(0)" ::: "memory");
  __syncthreads();
  if (threadIdx.x == 0) {
    __hip_atomic_fetch_add(cnt, 1u, __ATOMIC_RELEASE, __HIP_MEMORY_SCOPE_AGENT);
    while (__hip_atomic_load(cnt, __ATOMIC_RELAXED, __HIP_MEMORY_SCOPE_AGENT) < tgt)
      __builtin_amdgcn_s_sleep(2);
    __builtin_amdgcn_fence(__ATOMIC_ACQUIRE, "agent");
  }
  __syncthreads();
}

// ---------------- persistent recurrent kernel (one chunk of 128 steps) ----------------
// 256 WGs x 128 thr; WG = (g=bid&7 batch-group of 32 rows, j=bid>>3 slice of 16 cols).
// LDS: gate weight slices hi+lo = 128 KB; m-strip weights hi+lo in registers.
__global__ __launch_bounds__(128, 1) void k_rec(
    const uint16_t* __restrict__ wrh, const uint16_t* __restrict__ wrl,
    const float* __restrict__ blob,
    const float* __restrict__ b_ih, const float* __restrict__ b_hh,
    const float* __restrict__ mx_b, const float* __restrict__ mh_b,
    const float* __restrict__ h0, const float* __restrict__ c0,
    const int* __restrict__ lengths,
    uint16_t* __restrict__ hbh, uint16_t* __restrict__ hbl,
    uint16_t* __restrict__ mbh, uint16_t* __restrict__ mbl,
    float* __restrict__ cbuf, uint32_t* __restrict__ flags,
    float* __restrict__ out, int chunk) {
  extern __shared__ char smraw[];
  s8v* SW = (s8v*)smraw;  // [plane 2][gate 4][kt 16][lane 64] 16B frags
  int tid = threadIdx.x, l = tid & 63, mt = tid >> 6;
  int g = blockIdx.x & 7, j = blockIdx.x >> 3;

  for (int p = 0; p < 2; ++p) {
    const uint16_t* wp = p ? wrl : wrh;
    for (int nt = 0; nt < 4; ++nt) {
      const s8v* src = (const s8v*)(wp + (size_t)(nt * 32 + j) * 8192);
#pragma unroll
      for (int it = 0; it < 8; ++it) SW[p * 4096 + nt * 1024 + it * 128 + tid] = src[it * 128 + tid];
    }
  }
  s8v wmh[16], wml[16];  // m-strip (mh_w) frags, register-resident
  {
    const s8v* sH = (const s8v*)(wrh + (size_t)(128 + j) * 8192);
    const s8v* sL = (const s8v*)(wrl + (size_t)(128 + j) * 8192);
#pragma unroll
    for (int kt = 0; kt < 16; ++kt) { wmh[kt] = sH[kt * 64 + l]; wml[kt] = sL[kt * 64 + l]; }
  }
  int cidx = l & 15, rq = l >> 4;
  int hc = j * 16 + cidx;
  float mhb = mh_b[hc], mxb = mx_b[hc];
  float bsum[4];
#pragma unroll
  for (int nt = 0; nt < 4; ++nt) bsum[nt] = b_ih[nt * 512 + hc] + b_hh[nt * 512 + hc];
  int rowA = g * 32 + mt * 16 + cidx;        // A-frag row (global batch row)
  int kofs = rq * 8;
  int rowC0 = g * 32 + mt * 16 + rq * 4;     // C-frag row base
  float creg[4];
  int lenr[4];
#pragma unroll
  for (int ri = 0; ri < 4; ++ri) {
    int r = rowC0 + ri;
    lenr[ri] = lengths[r];
    creg[ri] = (chunk == 0) ? c0[hc] : cbuf[(size_t)r * 512 + hc];
  }
  if (chunk == 0) {
#pragma unroll
    for (int ri = 0; ri < 4; ++ri) {
      int r = rowC0 + ri;
      uint16_t hi, lo;
      split2(h0[hc], hi, lo);
      hbh[(size_t)r * 512 + hc] = hi;
      hbl[(size_t)r * 512 + hc] = lo;
    }
  }
  uint32_t* cnt = flags + g * 16;
  uint32_t ep = 1;
  grp_barrier(cnt, 32u * ep);  // h planes ready (also covers LDS fill via its syncthreads)

  for (int t = 0; t < 128; ++t) {
    size_t bb = ((size_t)(t * 160 + j) * 8 + g) * 512 + (size_t)(mt * 16 + rq * 4) * 16 + cidx;
    // early blob loads (t-known; hide HBM latency under MFMA)
    float bxm[4], bg[4][4];
#pragma unroll
    for (int ri = 0; ri < 4; ++ri) {
      bxm[ri] = blob[bb + 524288 + ri * 16];
#pragma unroll
      for (int nt = 0; nt < 4; ++nt) bg[nt][ri] = blob[bb + nt * 131072 + ri * 16];
    }
    // ---- P1: m = (xm + mx_b) * (h @ mh_w^T + mh_b) ----
    s8v ah[16], al[16];
    {
      const uint16_t* hr = hbh + (size_t)rowA * 512 + kofs;
      const uint16_t* lr = hbl + (size_t)rowA * 512 + kofs;
#pragma unroll
      for (int kt = 0; kt < 16; ++kt) {
        ah[kt] = *(const s8v*)(hr + kt * 32);
        al[kt] = *(const s8v*)(lr + kt * 32);
      }
    }
    f4v a1a0 = (f4v){0,0,0,0}, a1a1 = (f4v){0,0,0,0}, a1c0 = (f4v){0,0,0,0}, a1c1 = (f4v){0,0,0,0};
#pragma unroll
    for (int kt = 0; kt < 16; kt += 2) {
      a1a0 = mf(ah[kt], wmh[kt], a1a0);
      a1a1 = mf(ah[kt + 1], wmh[kt + 1], a1a1);
    }
#pragma unroll
    for (int kt = 0; kt < 16; ++kt) {
      a1c0 = mf(ah[kt], wml[kt], a1c0);
      a1c1 = mf(al[kt], wmh[kt], a1c1);
    }
#pragma unroll
    for (int ri = 0; ri < 4; ++ri) {
      float hv = a1a0[ri] + a1a1[ri] + (a1c0[ri] + a1c1[ri]) * ISC + mhb;
      float mv = (bxm[ri] + mxb) * hv;
      uint16_t hi, lo;
      split2(mv, hi, lo);
      mbh[(size_t)(rowC0 + ri) * 512 + hc] = hi;
      mbl[(size_t)(rowC0 + ri) * 512 + hc] = lo;
    }
    ++ep;
    grp_barrier(cnt, 32u * ep);
    // ---- P2: gates = xg + m @ W_hh^T + b; update c,h ----
    {
      const uint16_t* hr = mbh + (size_t)rowA * 512 + kofs;
      const uint16_t* lr = mbl + (size_t)rowA * 512 + kofs;
#pragma unroll
      for (int kt = 0; kt < 16; ++kt) {
        ah[kt] = *(const s8v*)(hr + kt * 32);
        al[kt] = *(const s8v*)(lr + kt * 32);
      }
    }
    f4v p2a[4], p2c[4];
#pragma unroll
    for (int nt = 0; nt < 4; ++nt) { p2a[nt] = (f4v){0,0,0,0}; p2c[nt] = (f4v){0,0,0,0}; }
#pragma unroll
    for (int kt = 0; kt < 16; ++kt)
#pragma unroll
      for (int nt = 0; nt < 4; ++nt) p2a[nt] = mf(ah[kt], SW[nt * 1024 + kt * 64 + l], p2a[nt]);
#pragma unroll
    for (int kt = 0; kt < 16; ++kt)
#pragma unroll
      for (int nt = 0; nt < 4; ++nt) {
        p2c[nt] = mf(ah[kt], SW[4096 + nt * 1024 + kt * 64 + l], p2c[nt]);
        p2c[nt] = mf(al[kt], SW[nt * 1024 + kt * 64 + l], p2c[nt]);
      }
#pragma unroll
    for (int ri = 0; ri < 4; ++ri) {
      float gi = p2a[0][ri] + p2c[0][ri] * ISC + bsum[0] + bg[0][ri];
      float gf = p2a[1][ri] + p2c[1][ri] * ISC + bsum[1] + bg[1][ri];
      float gc = p2a[2][ri] + p2c[2][ri] * ISC + bsum[2] + bg[2][ri];
      float go = p2a[3][ri] + p2c[3][ri] * ISC + bsum[3] + bg[3][ri];
      float iv = sigm(gi), fv = sigm(gf), gv = tanh_f(gc), ov = sigm(go);
      float cn = fv * creg[ri] + iv * gv;
      float hn = ov * tanh_f(cn);
      bool act = (chunk * 128 + t) < lenr[ri];
      if (act) {
        creg[ri] = cn;
        uint16_t hi, lo;
        split2(hn, hi, lo);
        hbh[(size_t)(rowC0 + ri) * 512 + hc] = hi;
        hbl[(size_t)(rowC0 + ri) * 512 + hc] = lo;
      }
    }
    ++ep;
    grp_barrier(cnt, 32u * ep);
  }
#pragma unroll
  for (int ri = 0; ri < 4; ++ri) {
    cbuf[(size_t)(rowC0 + ri) * 512 + hc] = creg[ri];
    if (chunk == 3) out[(size_t)(rowC0 + ri) * 512 + hc] = creg[ri];
  }
}

extern "C" void kernel_launch(void* const* d_in, const int* in_sizes, int n_in,
                              void* d_out, int out_size, void* d_ws, size_t ws_size,
                              hipStream_t stream) {
  (void)in_sizes; (void)n_in; (void)out_size;
  const float* x = (const float*)d_in[0];
  const int* lengths = (const int*)d_in[1];  // harness: integer inputs are int32
  const float* W_ih = (const float*)d_in[2];
  const float* W_hh = (const float*)d_in[3];
  const float* b_ih = (const float*)d_in[4];
  const float* b_hh = (const float*)d_in[5];
  const float* mx_w = (const float*)d_in[6];
  const float* mx_b = (const float*)d_in[7];
  const float* mh_w = (const float*)d_in[8];
  const float* mh_b = (const float*)d_in[9];
  const float* h0 = (const float*)d_in[10];
  const float* c0 = (const float*)d_in[11];

  if (ws_size < 616038912ull) return;  // clean failure signal (absmax would be 2.3906)

  char* ws = (char*)d_ws;
  uint16_t* xh = (uint16_t*)(ws);
  uint16_t* xl = (uint16_t*)(ws + 134217728ull);
  uint16_t* wpre_h = (uint16_t*)(ws + 268435456ull);
  uint16_t* wpre_l = (uint16_t*)(ws + 271056896ull);
  uint16_t* wrec_h = (uint16_t*)(ws + 273678336ull);
  uint16_t* wrec_l = (uint16_t*)(ws + 276299776ull);
  float* blob = (float*)(ws + 278921216ull);
  uint16_t* hbh = (uint16_t*)(ws + 614465536ull);
  uint16_t* hbl = (uint16_t*)(ws + 614727680ull);
  uint16_t* mbh = (uint16_t*)(ws + 614989824ull);
  uint16_t* mbl = (uint16_t*)(ws + 615251968ull);
  float* cbuf = (float*)(ws + 615514112ull);
  uint32_t* flags = (uint32_t*)(ws + 616038400ull);

  k_split<<<32768, 256, 0, stream>>>(x, xh, xl, 67108864L);
  k_packw<<<2560, 64, 0, stream>>>(W_ih, mx_w, wpre_h, wpre_l);
  k_packw<<<2560, 64, 0, stream>>>(W_hh, mh_w, wrec_h, wrec_l);
  hipFuncSetAttribute(reinterpret_cast<const void*>(k_rec),
                      hipFuncAttributeMaxDynamicSharedMemorySize, 131072);
  for (int c = 0; c < 4; ++c) {
    k_gemm3<<<dim3(20, 256), 256, 0, stream>>>(xh, xl, wpre_h, wpre_l, blob, c * 32768);
    hipMemsetAsync(flags, 0, 512, stream);
    k_rec<<<256, 128, 131072, stream>>>(wrec_h, wrec_l, blob, b_ih, b_hh, mx_b, mh_b,
                                        h0, c0, lengths, hbh, hbl, mbh, mbl, cbuf,
                                        flags, (float*)d_out, c);
  }
}

// Round 4
// 8749.474 us; speedup vs baseline: 1.3587x; 1.3587x over previous
//
#include <hip/hip_runtime.h>
#include <stdint.h>

// mLSTM T=512,B=256,I=H=512 — fp32-equivalent via fp16 hi/lo MFMA (3-pass).
// Round 4: fence-free recurrent phase. h/m state exchanged as packed u32
// (hi|lo<<16) via RELAXED+AGENT scoped atomics (coherent, no wbl2/inv);
// group barrier = vmcnt(0) + relaxed agent counter.
// ws layout (bytes):
//   xh     @ 0          x hi fp16                 134,217,728
//   xl     @ 134217728  x lo fp16 (scaled 2^11)   134,217,728
//   wpre_h @ 268435456  [W_ih;mx_w] frags hi        2,621,440
//   wpre_l @ 271056896  lo                          2,621,440
//   wrec_h @ 273678336  [W_hh;mh_w] frags hi        2,621,440
//   wrec_l @ 276299776  lo                          2,621,440
//   blob   @ 278921216  xg/xm fp32, 1 chunk (128 steps) 335,544,320
//   hpk    @ 614465536  h state packed u32           524,288
//   mpk    @ 614989824  m state packed u32           524,288
//   cbuf   @ 615514112  c state fp32                 524,288
//   flags  @ 616038400  8 barrier counters               512
// total 616,038,912

typedef __attribute__((ext_vector_type(8))) short s8v;
typedef __attribute__((ext_vector_type(8))) _Float16 h8v;
typedef __attribute__((ext_vector_type(4))) float f4v;
typedef __attribute__((ext_vector_type(4))) uint32_t u4v;

union frag { s8v s; u4v u; };

#define SC 2048.0f
#define ISC (1.0f / 2048.0f)

__device__ __forceinline__ f4v mf(s8v a, s8v b, f4v c) {
  return __builtin_amdgcn_mfma_f32_16x16x32_f16(
      __builtin_bit_cast(h8v, a), __builtin_bit_cast(h8v, b), c, 0, 0, 0);
}
__device__ __forceinline__ uint16_t f2h(float x) {
  _Float16 h = (_Float16)x;
  return __builtin_bit_cast(uint16_t, h);
}
__device__ __forceinline__ void split2(float v, uint16_t& hi, uint16_t& lo) {
  _Float16 h = (_Float16)v;
  float r = v - (float)h;
  hi = __builtin_bit_cast(uint16_t, h);
  lo = f2h(r * SC);
}
__device__ __forceinline__ float sigm(float x) { return 1.0f / (1.0f + __expf(-x)); }
__device__ __forceinline__ float tanh_f(float x) { return 1.0f - 2.0f / (__expf(2.0f * x) + 1.0f); }

// ---------------- split x fp32 -> fp16 hi/lo planes ----------------
__global__ __launch_bounds__(256) void k_split(const float* __restrict__ x,
                                               uint16_t* __restrict__ xh,
                                               uint16_t* __restrict__ xl, long n) {
  long i = ((long)blockIdx.x * 256 + threadIdx.x) * 8;
  if (i >= n) return;
  float4 a = *(const float4*)(x + i);
  float4 b = *(const float4*)(x + i + 4);
  union { uint16_t u[8]; s8v v; } oh, ol;
  float vv[8] = {a.x, a.y, a.z, a.w, b.x, b.y, b.z, b.w};
#pragma unroll
  for (int k = 0; k < 8; ++k) split2(vv[k], oh.u[k], ol.u[k]);
  *(s8v*)(xh + i) = oh.v;
  *(s8v*)(xl + i) = ol.v;
}

// ---------------- pack weights into MFMA B-fragment order, hi/lo ----------------
// strip s<128: gate col 16s+c from Wg; s>=128: col 16(s-128)+c from Wm
// frag[(s*16+kt)*512 + lane*8 + j] = W_col[k = kt*32 + 8*(lane>>4) + j]
__global__ __launch_bounds__(64) void k_packw(const float* __restrict__ Wg,
                                              const float* __restrict__ Wm,
                                              uint16_t* __restrict__ wh,
                                              uint16_t* __restrict__ wl) {
  int s = blockIdx.x >> 4, kt = blockIdx.x & 15, l = threadIdx.x;
  const float* src = (s < 128) ? (Wg + (size_t)(s * 16 + (l & 15)) * 512)
                               : (Wm + (size_t)((s - 128) * 16 + (l & 15)) * 512);
  int k0 = kt * 32 + (l >> 4) * 8;
  float4 a = *(const float4*)(src + k0);
  float4 b = *(const float4*)(src + k0 + 4);
  union { uint16_t u[8]; s8v v; } oh, ol;
  float vv[8] = {a.x, a.y, a.z, a.w, b.x, b.y, b.z, b.w};
#pragma unroll
  for (int k = 0; k < 8; ++k) split2(vv[k], oh.u[k], ol.u[k]);
  size_t adr = ((size_t)(s * 16 + kt) * 64 + l) * 8;
  *(s8v*)(wh + adr) = oh.v;
  *(s8v*)(wl + adr) = ol.v;
}

// ---------------- one K-pass of the precompute GEMM ----------------
__device__ __forceinline__ void gpass(const uint16_t* __restrict__ Ap,
                                      const uint16_t* __restrict__ Bp,
                                      s8v* Asm, s8v* Bsm, int rowbase, int s0,
                                      f4v (&acc)[4][4]) {
  int tid = threadIdx.x;
  int wv = tid >> 6, l = tid & 63, wm = wv >> 1, wn = wv & 1;
  int arow = tid >> 1, ahalf = tid & 1, swz = (arow & 7) << 4;
  for (int ks = 0; ks < 8; ++ks) {
    __syncthreads();
    const uint16_t* asrc = Ap + (size_t)(rowbase + arow) * 512 + ks * 64;
#pragma unroll
    for (int q = 0; q < 4; ++q) {
      int pb = ahalf * 64 + q * 16;  // physical byte within 128B row
      Asm[arow * 8 + (pb >> 4)] = *(const s8v*)(asrc + ((pb ^ swz) >> 1));
    }
#pragma unroll
    for (int q = 0; q < 4; ++q) {
      int ofs = tid * 64 + q * 16;
      int si = ofs >> 11, kti = (ofs >> 10) & 1, inner = ofs & 1023;
      Bsm[ofs >> 4] =
          *(const s8v*)(Bp + (size_t)((s0 + si) * 16 + ks * 2 + kti) * 512 + (inner >> 1));
    }
    __syncthreads();
#pragma unroll
    for (int kti = 0; kti < 2; ++kti) {
      s8v a[4], b[4];
#pragma unroll
      for (int i = 0; i < 4; ++i) {
        int row = wm * 64 + i * 16 + (l & 15);
        int lb = kti * 64 + (l >> 4) * 16;  // logical byte within row
        a[i] = Asm[row * 8 + ((lb ^ ((l & 7) << 4)) >> 4)];
      }
#pragma unroll
      for (int jj = 0; jj < 4; ++jj) b[jj] = Bsm[((wn * 4 + jj) * 2 + kti) * 64 + l];
#pragma unroll
      for (int i = 0; i < 4; ++i)
#pragma unroll
        for (int jj = 0; jj < 4; ++jj) acc[i][jj] = mf(a[i], b[jj], acc[i][jj]);
    }
  }
}

// ---------------- 3-pass precompute GEMM, fp32 blob out ----------------
// blob tile layout per chunk: [(t*160+s)*8+g]*512 + rr*16 + c  (fp32)
__global__ __launch_bounds__(256, 2) void k_gemm3(const uint16_t* __restrict__ xh,
                                                  const uint16_t* __restrict__ xl,
                                                  const uint16_t* __restrict__ wh,
                                                  const uint16_t* __restrict__ wl,
                                                  float* __restrict__ blob, int row0) {
  __shared__ s8v Asm[1024], Bsm[1024];
  f4v acc_a[4][4], acc_c[4][4];
#pragma unroll
  for (int i = 0; i < 4; ++i)
#pragma unroll
    for (int jj = 0; jj < 4; ++jj) {
      acc_a[i][jj] = (f4v){0.f, 0.f, 0.f, 0.f};
      acc_c[i][jj] = (f4v){0.f, 0.f, 0.f, 0.f};
    }
  int s0 = blockIdx.x * 8, r0 = blockIdx.y * 128;
  int rowbase = row0 + r0;
  gpass(xh, wh, Asm, Bsm, rowbase, s0, acc_a);
  gpass(xh, wl, Asm, Bsm, rowbase, s0, acc_c);
  gpass(xl, wh, Asm, Bsm, rowbase, s0, acc_c);
  int tid = threadIdx.x, wv = tid >> 6, l = tid & 63, wm = wv >> 1, wn = wv & 1;
#pragma unroll
  for (int i = 0; i < 4; ++i)
#pragma unroll
    for (int jj = 0; jj < 4; ++jj) {
      int s = s0 + wn * 4 + jj;
#pragma unroll
      for (int ri = 0; ri < 4; ++ri) {
        int trow = r0 + wm * 64 + i * 16 + (l >> 4) * 4 + ri;  // chunk-local row
        int tt = trow >> 8, gg = (trow >> 5) & 7, rr = trow & 31;
        size_t adr = ((size_t)(tt * 160 + s) * 8 + gg) * 512 + rr * 16 + (l & 15);
        blob[adr] = acc_a[i][jj][ri] + acc_c[i][jj][ri] * ISC;
      }
    }
}

// ---------------- fence-free group barrier (32 WGs per batch-group) ----------------
// Correctness: every wave drains vmcnt(0) (its state stores reach the agent
// coherence point) BEFORE __syncthreads; leader's relaxed agent add is thus
// ordered after all of this WG's state stores. Readers access state only via
// RELAXED+AGENT atomic loads (bypass stale local caches) after observing the
// counter, so no cache-maintenance (wbl2/inv) is needed.
__device__ __forceinline__ void grp_barrier(uint32_t* cnt, uint32_t tgt) {
  asm volatile("s_waitcnt vmcnt(0)" ::: "memory");
  __syncthreads();
  if (threadIdx.x == 0) {
    __hip_atomic_fetch_add(cnt, 1u, __ATOMIC_RELAXED, __HIP_MEMORY_SCOPE_AGENT);
    while (__hip_atomic_load(cnt, __ATOMIC_RELAXED, __HIP_MEMORY_SCOPE_AGENT) < tgt)
      __builtin_amdgcn_s_sleep(2);
  }
  __syncthreads();
}

__device__ __forceinline__ void st_state(uint32_t* p, uint32_t v) {
  __hip_atomic_store(p, v, __ATOMIC_RELAXED, __HIP_MEMORY_SCOPE_AGENT);
}

// load 16 kt-fragments (hi+lo planes) from packed state, agent-coherent
__device__ __forceinline__ void ld_state(const uint32_t* base, s8v (&ah)[16], s8v (&al)[16]) {
  unsigned long long* q = (unsigned long long*)base;
#pragma unroll
  for (int kt = 0; kt < 16; ++kt) {
    frag fh, fl;
#pragma unroll
    for (int qq = 0; qq < 4; ++qq) {
      unsigned long long w =
          __hip_atomic_load(q + kt * 16 + qq, __ATOMIC_RELAXED, __HIP_MEMORY_SCOPE_AGENT);
      uint32_t a = (uint32_t)w, b = (uint32_t)(w >> 32);
      fh.u[qq] = (a & 0xFFFFu) | (b << 16);
      fl.u[qq] = (a >> 16) | (b & 0xFFFF0000u);
    }
    ah[kt] = fh.s;
    al[kt] = fl.s;
  }
}

// ---------------- persistent recurrent kernel (one chunk of 128 steps) ----------------
// 256 WGs x 128 thr; WG = (g=bid&7 batch-group of 32 rows, j=bid>>3 slice of 16 cols).
// LDS: gate weight slices hi+lo = 128 KB; m-strip weights hi+lo in registers.
__global__ __launch_bounds__(128, 1) void k_rec(
    const uint16_t* __restrict__ wrh, const uint16_t* __restrict__ wrl,
    const float* __restrict__ blob,
    const float* __restrict__ b_ih, const float* __restrict__ b_hh,
    const float* __restrict__ mx_b, const float* __restrict__ mh_b,
    const float* __restrict__ h0, const float* __restrict__ c0,
    const int* __restrict__ lengths,
    uint32_t* __restrict__ hpk, uint32_t* __restrict__ mpk,
    float* __restrict__ cbuf, uint32_t* __restrict__ flags,
    float* __restrict__ out, int chunk) {
  extern __shared__ char smraw[];
  s8v* SW = (s8v*)smraw;  // [plane 2][gate 4][kt 16][lane 64] 16B frags
  int tid = threadIdx.x, l = tid & 63, mt = tid >> 6;
  int g = blockIdx.x & 7, j = blockIdx.x >> 3;

  for (int p = 0; p < 2; ++p) {
    const uint16_t* wp = p ? wrl : wrh;
    for (int nt = 0; nt < 4; ++nt) {
      const s8v* src = (const s8v*)(wp + (size_t)(nt * 32 + j) * 8192);
#pragma unroll
      for (int it = 0; it < 8; ++it) SW[p * 4096 + nt * 1024 + it * 128 + tid] = src[it * 128 + tid];
    }
  }
  s8v wmh[16], wml[16];  // m-strip (mh_w) frags, register-resident
  {
    const s8v* sH = (const s8v*)(wrh + (size_t)(128 + j) * 8192);
    const s8v* sL = (const s8v*)(wrl + (size_t)(128 + j) * 8192);
#pragma unroll
    for (int kt = 0; kt < 16; ++kt) { wmh[kt] = sH[kt * 64 + l]; wml[kt] = sL[kt * 64 + l]; }
  }
  int cidx = l & 15, rq = l >> 4;
  int hc = j * 16 + cidx;
  float mhb = mh_b[hc], mxb = mx_b[hc];
  float bsum[4];
#pragma unroll
  for (int nt = 0; nt < 4; ++nt) bsum[nt] = b_ih[nt * 512 + hc] + b_hh[nt * 512 + hc];
  int rowA = g * 32 + mt * 16 + cidx;        // A-frag row (global batch row)
  int kofs = rq * 8;
  int rowC0 = g * 32 + mt * 16 + rq * 4;     // C-frag row base
  float creg[4];
  int lenr[4];
#pragma unroll
  for (int ri = 0; ri < 4; ++ri) {
    int r = rowC0 + ri;
    lenr[ri] = lengths[r];
    creg[ri] = (chunk == 0) ? c0[hc] : cbuf[(size_t)r * 512 + hc];
  }
  if (chunk == 0) {
    uint16_t hi, lo;
    split2(h0[hc], hi, lo);
    uint32_t pk = (uint32_t)hi | ((uint32_t)lo << 16);
#pragma unroll
    for (int ri = 0; ri < 4; ++ri) st_state(&hpk[(size_t)(rowC0 + ri) * 512 + hc], pk);
  }
  uint32_t* cnt = flags + g * 16;
  uint32_t ep = 1;
  grp_barrier(cnt, 32u * ep);  // h state ready (also covers LDS fill via its syncthreads)

  for (int t = 0; t < 128; ++t) {
    size_t bb = ((size_t)(t * 160 + j) * 8 + g) * 512 + (size_t)(mt * 16 + rq * 4) * 16 + cidx;
    // early blob loads (t-known; hide HBM latency under MFMA)
    float bxm[4], bg[4][4];
#pragma unroll
    for (int ri = 0; ri < 4; ++ri) {
      bxm[ri] = blob[bb + 524288 + ri * 16];
#pragma unroll
      for (int nt = 0; nt < 4; ++nt) bg[nt][ri] = blob[bb + nt * 131072 + ri * 16];
    }
    // ---- P1: m = (xm + mx_b) * (h @ mh_w^T + mh_b) ----
    s8v ah[16], al[16];
    ld_state(hpk + (size_t)rowA * 512 + kofs, ah, al);
    f4v a1a0 = (f4v){0,0,0,0}, a1a1 = (f4v){0,0,0,0}, a1c0 = (f4v){0,0,0,0}, a1c1 = (f4v){0,0,0,0};
#pragma unroll
    for (int kt = 0; kt < 16; kt += 2) {
      a1a0 = mf(ah[kt], wmh[kt], a1a0);
      a1a1 = mf(ah[kt + 1], wmh[kt + 1], a1a1);
    }
#pragma unroll
    for (int kt = 0; kt < 16; ++kt) {
      a1c0 = mf(ah[kt], wml[kt], a1c0);
      a1c1 = mf(al[kt], wmh[kt], a1c1);
    }
#pragma unroll
    for (int ri = 0; ri < 4; ++ri) {
      float hv = a1a0[ri] + a1a1[ri] + (a1c0[ri] + a1c1[ri]) * ISC + mhb;
      float mv = (bxm[ri] + mxb) * hv;
      uint16_t hi, lo;
      split2(mv, hi, lo);
      st_state(&mpk[(size_t)(rowC0 + ri) * 512 + hc], (uint32_t)hi | ((uint32_t)lo << 16));
    }
    ++ep;
    grp_barrier(cnt, 32u * ep);
    // ---- P2: gates = xg + m @ W_hh^T + b; update c,h ----
    ld_state(mpk + (size_t)rowA * 512 + kofs, ah, al);
    f4v p2a[4], p2c[4];
#pragma unroll
    for (int nt = 0; nt < 4; ++nt) { p2a[nt] = (f4v){0,0,0,0}; p2c[nt] = (f4v){0,0,0,0}; }
#pragma unroll
    for (int kt = 0; kt < 16; ++kt)
#pragma unroll
      for (int nt = 0; nt < 4; ++nt) p2a[nt] = mf(ah[kt], SW[nt * 1024 + kt * 64 + l], p2a[nt]);
#pragma unroll
    for (int kt = 0; kt < 16; ++kt)
#pragma unroll
      for (int nt = 0; nt < 4; ++nt) {
        p2c[nt] = mf(ah[kt], SW[4096 + nt * 1024 + kt * 64 + l], p2c[nt]);
        p2c[nt] = mf(al[kt], SW[nt * 1024 + kt * 64 + l], p2c[nt]);
      }
#pragma unroll
    for (int ri = 0; ri < 4; ++ri) {
      float gi = p2a[0][ri] + p2c[0][ri] * ISC + bsum[0] + bg[0][ri];
      float gf = p2a[1][ri] + p2c[1][ri] * ISC + bsum[1] + bg[1][ri];
      float gc = p2a[2][ri] + p2c[2][ri] * ISC + bsum[2] + bg[2][ri];
      float go = p2a[3][ri] + p2c[3][ri] * ISC + bsum[3] + bg[3][ri];
      float iv = sigm(gi), fv = sigm(gf), gv = tanh_f(gc), ov = sigm(go);
      float cn = fv * creg[ri] + iv * gv;
      float hn = ov * tanh_f(cn);
      bool act = (chunk * 128 + t) < lenr[ri];
      if (act) {
        creg[ri] = cn;
        uint16_t hi, lo;
        split2(hn, hi, lo);
        st_state(&hpk[(size_t)(rowC0 + ri) * 512 + hc], (uint32_t)hi | ((uint32_t)lo << 16));
      }
    }
    ++ep;
    grp_barrier(cnt, 32u * ep);
  }
#pragma unroll
  for (int ri = 0; ri < 4; ++ri) {
    cbuf[(size_t)(rowC0 + ri) * 512 + hc] = creg[ri];
    if (chunk == 3) out[(size_t)(rowC0 + ri) * 512 + hc] = creg[ri];
  }
}

extern "C" void kernel_launch(void* const* d_in, const int* in_sizes, int n_in,
                              void* d_out, int out_size, void* d_ws, size_t ws_size,
                              hipStream_t stream) {
  (void)in_sizes; (void)n_in; (void)out_size;
  const float* x = (const float*)d_in[0];
  const int* lengths = (const int*)d_in[1];  // harness: integer inputs are int32
  const float* W_ih = (const float*)d_in[2];
  const float* W_hh = (const float*)d_in[3];
  const float* b_ih = (const float*)d_in[4];
  const float* b_hh = (const float*)d_in[5];
  const float* mx_w = (const float*)d_in[6];
  const float* mx_b = (const float*)d_in[7];
  const float* mh_w = (const float*)d_in[8];
  const float* mh_b = (const float*)d_in[9];
  const float* h0 = (const float*)d_in[10];
  const float* c0 = (const float*)d_in[11];

  if (ws_size < 616038912ull) return;  // clean failure signal (absmax would be 2.3906)

  char* ws = (char*)d_ws;
  uint16_t* xh = (uint16_t*)(ws);
  uint16_t* xl = (uint16_t*)(ws + 134217728ull);
  uint16_t* wpre_h = (uint16_t*)(ws + 268435456ull);
  uint16_t* wpre_l = (uint16_t*)(ws + 271056896ull);
  uint16_t* wrec_h = (uint16_t*)(ws + 273678336ull);
  uint16_t* wrec_l = (uint16_t*)(ws + 276299776ull);
  float* blob = (float*)(ws + 278921216ull);
  uint32_t* hpk = (uint32_t*)(ws + 614465536ull);
  uint32_t* mpk = (uint32_t*)(ws + 614989824ull);
  float* cbuf = (float*)(ws + 615514112ull);
  uint32_t* flags = (uint32_t*)(ws + 616038400ull);

  k_split<<<32768, 256, 0, stream>>>(x, xh, xl, 67108864L);
  k_packw<<<2560, 64, 0, stream>>>(W_ih, mx_w, wpre_h, wpre_l);
  k_packw<<<2560, 64, 0, stream>>>(W_hh, mh_w, wrec_h, wrec_l);
  hipFuncSetAttribute(reinterpret_cast<const void*>(k_rec),
                      hipFuncAttributeMaxDynamicSharedMemorySize, 131072);
  for (int c = 0; c < 4; ++c) {
    k_gemm3<<<dim3(20, 256), 256, 0, stream>>>(xh, xl, wpre_h, wpre_l, blob, c * 32768);
    hipMemsetAsync(flags, 0, 512, stream);
    k_rec<<<256, 128, 131072, stream>>>(wrec_h, wrec_l, blob, b_ih, b_hh, mx_b, mh_b,
                                        h0, c0, lengths, hpk, mpk, cbuf,
                                        flags, (float*)d_out, c);
  }
}